// Round 8
// baseline (1433.359 us; speedup 1.0000x reference)
//
#include <hip/hip_runtime.h>

// GraphConv x3 on MI355X. R16: R15's two-stage edge binning with the queue
// aggregation FIXED. R15 bug: partition offset not 64-aligned (Npad=50000)
// -> straddling waves; `if (lane==s) atomicAdd` used a fixed leader lane
// that could be inactive -> lost/overwritten queue records. Now (a) leader =
// first active lane with seg==s (ffsll of ballot), (b) ncnt-zero range
// padded to 64 so edge-append waves are always full. Layers frozen = R14
// (async global_load_lds gather @ ~2.45 TB/s fetch floor). 5 dispatches.

#define C128 128
#define CAPN 64     // records per node; mean deg 16, Poisson tail ~1e-18
#define NSEG 8

typedef short s16x8 __attribute__((ext_vector_type(8)));
typedef float f32x4 __attribute__((ext_vector_type(4)));

__device__ __forceinline__ ushort f2bf(float f) {        // RNE fp32->bf16
  unsigned u = __builtin_bit_cast(unsigned, f);
  u = (u + 0x7FFFu + ((u >> 16) & 1u)) >> 16;
  return (ushort)u;
}
__device__ __forceinline__ float bflo(unsigned v) {
  return __builtin_bit_cast(float, v << 16);
}
__device__ __forceinline__ float bfhi(unsigned v) {
  return __builtin_bit_cast(float, v & 0xFFFF0000u);
}
__device__ __forceinline__ unsigned pack2(float lo, float hi) {
  return (unsigned)f2bf(lo) | ((unsigned)f2bf(hi) << 16);
}
// async 16B global->LDS; lane i deposits at l + i*16; g is per-lane.
__device__ __forceinline__ void gload_lds16(const void* g, void* l) {
  __builtin_amdgcn_global_load_lds(
      (const __attribute__((address_space(1))) void*)g,
      (__attribute__((address_space(3))) void*)l, 16, 0, 0);
}
// mask dtype probe: 1 if mask is int32 (all of first 16 words are 0/1),
// 0 if uint8 (byte-packed 0/1 -> words like 0x00010001 > 1).
__device__ __forceinline__ int probe_m32(const void* msk) {
  const uint4* p = (const uint4*)msk;
  int m32 = 1;
#pragma unroll
  for (int i = 0; i < 4; ++i) {
    uint4 q = p[i];
    if (q.x > 1u || q.y > 1u || q.z > 1u || q.w > 1u) m32 = 0;
  }
  return m32;
}

// ---------------------------------------------------------------------------
// prep: fused {input dropout fp32->bf16} + {weight pack} + {ncnt zero} +
// {nlist zero} + {bit-pack drop1/drop2} + {edge-pack queue append}.
// Thread partition (EVERY range 64-aligned so waves never straddle):
// [n4 dropout][98304 pack][NpadZ ncnt][nL4 nlist][2*NW kb][E edge-append].
// Wpack idx = (c*8+nt)*512 + lane*8 + j ->
//   W[o=nt*16+(lane&15)][k=(c&3)*32+(lane>>4)*8+j]; c<4 Wrel, c>=4 Wroot.
// kb layout: kb[node*4 + w] bit b = keep(channel w*32+b).
// queue: seg=(dst>>4)&7; rec = src<<16|dst; leader-based wave-agg append.
// ---------------------------------------------------------------------------
__global__ __launch_bounds__(256) void prep_kernel(const float* __restrict__ Wr0,
                                                   const float* __restrict__ Wt0,
                                                   const float* __restrict__ Wr1,
                                                   const float* __restrict__ Wt1,
                                                   const float* __restrict__ Wr2,
                                                   const float* __restrict__ Wt2,
                                                   ushort* __restrict__ Wpack,
                                                   const float* __restrict__ x,
                                                   const void* __restrict__ mask0,
                                                   const void* __restrict__ mask1,
                                                   const void* __restrict__ mask2,
                                                   const int* __restrict__ eidx,
                                                   ushort* __restrict__ hdA,
                                                   unsigned* __restrict__ kb1,
                                                   unsigned* __restrict__ kb2,
                                                   int n4,
                                                   int* __restrict__ ncnt,
                                                   int Npad, int NpadZ,
                                                   uint4* __restrict__ nlist4,
                                                   int nL4, int NW,
                                                   int* __restrict__ qcnt,
                                                   unsigned* __restrict__ queue,
                                                   int qcap, int E) {
  int t = blockIdx.x * 256 + threadIdx.x;
  if (t < n4) {
    int m32 = probe_m32(mask0);
    float4 v = ((const float4*)x)[t];
    int k0, k1, k2, k3;
    if (m32) {
      int4 m = ((const int4*)mask0)[t];
      k0 = m.x; k1 = m.y; k2 = m.z; k3 = m.w;
    } else {
      uchar4 m = ((const uchar4*)mask0)[t];
      k0 = m.x; k1 = m.y; k2 = m.z; k3 = m.w;
    }
    ushort4 r;
    r.x = k0 ? f2bf(v.x * 2.5f) : (ushort)0;
    r.y = k1 ? f2bf(v.y * 2.5f) : (ushort)0;
    r.z = k2 ? f2bf(v.z * 2.5f) : (ushort)0;
    r.w = k3 ? f2bf(v.w * 2.5f) : (ushort)0;
    ((ushort4*)hdA)[t] = r;
    return;
  }
  int u = t - n4;
  if (u < 3 * 32768) {
    int L = u >> 15;
    int r = u & 32767;
    int c = r >> 12;
    int nt = (r >> 9) & 7;
    int lane = (r >> 3) & 63;
    int j = r & 7;
    int o = nt * 16 + (lane & 15);
    int k = (c & 3) * 32 + (lane >> 4) * 8 + j;
    const float* src;
    if (L == 0)      src = (c < 4) ? Wr0 : Wt0;
    else if (L == 1) src = (c < 4) ? Wr1 : Wt1;
    else             src = (c < 4) ? Wr2 : Wt2;
    Wpack[u] = f2bf(src[o * C128 + k]);
    return;
  }
  u -= 3 * 32768;
  if (u < NpadZ) {
    if (u < Npad) ncnt[u] = 0;
    return;
  }
  u -= NpadZ;
  if (u < nL4) {
    uint4 zero; zero.x = 0; zero.y = 0; zero.z = 0; zero.w = 0;
    nlist4[u] = zero;
    return;
  }
  u -= nL4;
  if (u < 2 * NW) {
    const int L = (u >= NW);
    const int w = L ? u - NW : u;          // word id: node = w>>2, k = w&3
    const void* msk = L ? mask2 : mask1;
    const int n = w >> 2, k = w & 3;
    const int m32 = probe_m32(msk);
    unsigned wb = 0;
    if (m32) {
      const int4* b = (const int4*)msk + n * 32 + k * 8;
#pragma unroll
      for (int i = 0; i < 8; ++i) {
        int4 mm = b[i];
        wb |= (mm.x ? 1u : 0u) << (4 * i);
        wb |= (mm.y ? 1u : 0u) << (4 * i + 1);
        wb |= (mm.z ? 1u : 0u) << (4 * i + 2);
        wb |= (mm.w ? 1u : 0u) << (4 * i + 3);
      }
    } else {
      const uchar4* b = (const uchar4*)msk + n * 32 + k * 8;
#pragma unroll
      for (int i = 0; i < 8; ++i) {
        uchar4 mm = b[i];
        wb |= (mm.x ? 1u : 0u) << (4 * i);
        wb |= (mm.y ? 1u : 0u) << (4 * i + 1);
        wb |= (mm.z ? 1u : 0u) << (4 * i + 2);
        wb |= (mm.w ? 1u : 0u) << (4 * i + 3);
      }
    }
    (L ? kb2 : kb1)[n * 4 + k] = wb;
    return;
  }
  u -= 2 * NW;
  if (u < E) {
    // ---- edge-pack append (range 64-aligned; E % 64 == 0 -> full waves) ----
    const int lane = threadIdx.x & 63;
    unsigned long long be = __ballot(eidx[2 * lane + 1] != 0);
    const int e64 = (be == 0ull);   // 1 = edges are int64
    int src, dst;
    if (e64) { src = eidx[2 * u]; dst = eidx[2 * E + 2 * u]; }
    else     { src = eidx[u];     dst = eidx[E + u]; }
    const int seg = (dst >> 4) & (NSEG - 1);
    const unsigned rec = ((unsigned)src << 16) | (unsigned)dst;
    int pos = 0;
#pragma unroll
    for (int s = 0; s < NSEG; ++s) {
      unsigned long long bm = __ballot(seg == s);
      if (bm == 0ull) continue;                       // wave-uniform
      const int leader = (int)(__ffsll((long long)bm) - 1);
      int b = 0;
      if (lane == leader) b = atomicAdd(&qcnt[s], __popcll(bm));
      b = __shfl(b, leader, 64);
      if (seg == s)
        pos = b + __popcll(bm & ((1ull << lane) - 1ull));
    }
    if (pos < qcap) queue[seg * qcap + pos] = rec;
  }
}

// ---------------------------------------------------------------------------
// fillb: scatter-only. seg = blockIdx&7 (XCD round-robin proxy, same proxy
// as the layer grid's bucket16 mapping since seg=(dst>>4)&7). Reads its own
// compact queue (coalesced 4B) and scatters XCD-locally -> nlist/ncnt lines
// written by one XCD and later read by layer blocks on that same XCD.
// ---------------------------------------------------------------------------
__global__ __launch_bounds__(256) void fillb_kernel(const int* __restrict__ qcnt,
                                                    const unsigned* __restrict__ queue,
                                                    int* __restrict__ ncnt,
                                                    ushort* __restrict__ nlist,
                                                    int qcap) {
  const int seg = blockIdx.x & (NSEG - 1);
  int qn = qcnt[seg];
  if (qn > qcap) qn = qcap;
  const int i = (blockIdx.x >> 3) * 256 + threadIdx.x;
  if (i >= qn) return;
  const unsigned rec = queue[seg * qcap + i];
  const int dst = (int)(rec & 0xFFFFu);
  const int src = (int)(rec >> 16);
  int pos = atomicAdd(&ncnt[dst], 1);
  if (pos < CAPN) nlist[(size_t)dst * CAPN + pos] = (ushort)src;
}

// ---------------------------------------------------------------------------
// Fused layer: block = 16 nodes, 4 waves, wave w owns nodes 4w..4w+3.
//  0) stage: coalesced 512B list load per wave -> wl LDS + 16 coalesced
//     degree loads.
//  1) gather: async global_load_lds chunks (4 nodes x 4 edges = 4KB),
//     double-buffered; counted s_waitcnt vmcnt(4) mid-loop; predicated fma;
//     pad edges read row 0 (nlist zero-filled). xor-shfl reduce over quads;
//     quad-0 deposits bf16 rows into As. 1 barrier.
//  2) MFMA: wave w -> col tiles {2w,2w+1}; agg half from LDS, root half
//     loaded post-gather; B frags from Wpack (L2-hot).
//  3) epilogue: mode=1 ReLU + bit-packed next-dropout -> bf16 (mask word =
//     kb[node*4+wave], bit j*16+l16); mode=0 +bias -> fp32.
// ---------------------------------------------------------------------------
__global__ __launch_bounds__(256, 4) void layer_kernel(const ushort* __restrict__ hd,
                                                       const int* __restrict__ ncnt,
                                                       const ushort* __restrict__ nlist,
                                                       const ushort* __restrict__ Wpack,
                                                       const float* __restrict__ bias,
                                                       const unsigned* __restrict__ kb,
                                                       void* __restrict__ outp,
                                                       int mode, int N) {
  __shared__ ushort wl[16][CAPN];       // per-wave 4-row slices (512B/wave)
  __shared__ ushort As[16][136];        // 16 node rows, pad 8 (16B rows)
  __shared__ ushort gbuf[4][2][2048];   // per-wave dbuf: 2 x 4KB chunks

  const int tid = threadIdx.x;
  const int wave = tid >> 6, lane = tid & 63;
  const int quad = lane >> 4, l16 = lane & 15, co = l16 * 8;
  const int node0 = blockIdx.x * 16;
  const int nb0 = wave * 4;

  // ---- 0) stage: degrees + this wave's 4 node lists ----
  int deg16 = ncnt[node0 + l16];
  if (deg16 > CAPN) deg16 = CAPN;
  ((uint2*)&wl[nb0][0])[lane] =
      ((const uint2*)(nlist + (size_t)(node0 + nb0) * CAPN))[lane];

  int dc[4];
#pragma unroll
  for (int t = 0; t < 4; ++t) dc[t] = __shfl(deg16, nb0 + t, 64);
  int m = dc[0];
  if (dc[1] > m) m = dc[1];
  if (dc[2] > m) m = dc[2];
  if (dc[3] > m) m = dc[3];

  // ---- 1) gather: async LDS chunks, 4 edges/node/chunk ----
  const ushort* base = hd + co;
  float ag[4][8];
#pragma unroll
  for (int t = 0; t < 4; ++t)
#pragma unroll
    for (int i = 0; i < 8; ++i) ag[t][i] = 0.f;

  const int C = (m + 3) >> 2;          // wave-uniform chunk count (<=16)

#define ISSUE(c_, b_)                                                     \
  {                                                                       \
    const int e_ = ((c_) << 2) + quad;                                    \
    _Pragma("unroll")                                                     \
    for (int t_ = 0; t_ < 4; ++t_) {                                      \
      const ushort* g_ = base + (size_t)wl[nb0 + t_][e_] * C128;          \
      gload_lds16(g_, &gbuf[wave][b_][t_ * 512]);                         \
    }                                                                     \
  }

  if (C > 0) ISSUE(0, 0)
  if (C > 1) ISSUE(1, 1)

  for (int c = 0; c < C; ++c) {
    if (c + 1 < C) {
      asm volatile("s_waitcnt vmcnt(4)" ::: "memory");   // chunk c landed
    } else {
      asm volatile("s_waitcnt vmcnt(0)" ::: "memory");
    }
    __builtin_amdgcn_sched_barrier(0);
    const ushort* rb = &gbuf[wave][c & 1][lane * 8];
    const int e0 = (c << 2) + quad;
#pragma unroll
    for (int t = 0; t < 4; ++t) {
      uint4 v = *(const uint4*)(rb + t * 512);
      const float k = (e0 < dc[t]) ? 1.f : 0.f;
      ag[t][0] = fmaf(k, bflo(v.x), ag[t][0]);
      ag[t][1] = fmaf(k, bfhi(v.x), ag[t][1]);
      ag[t][2] = fmaf(k, bflo(v.y), ag[t][2]);
      ag[t][3] = fmaf(k, bfhi(v.y), ag[t][3]);
      ag[t][4] = fmaf(k, bflo(v.z), ag[t][4]);
      ag[t][5] = fmaf(k, bfhi(v.z), ag[t][5]);
      ag[t][6] = fmaf(k, bflo(v.w), ag[t][6]);
      ag[t][7] = fmaf(k, bfhi(v.w), ag[t][7]);
    }
    if (c + 2 < C) ISSUE(c + 2, c & 1)
  }
#undef ISSUE

#pragma unroll
  for (int t = 0; t < 4; ++t) {
#pragma unroll
    for (int i = 0; i < 8; ++i) {
      float v = ag[t][i];
      v += __shfl_xor(v, 16, 64);
      v += __shfl_xor(v, 32, 64);
      ag[t][i] = v;
    }
    if (quad == 0) {
      uint4 p;
      p.x = pack2(ag[t][0], ag[t][1]);
      p.y = pack2(ag[t][2], ag[t][3]);
      p.z = pack2(ag[t][4], ag[t][5]);
      p.w = pack2(ag[t][6], ag[t][7]);
      *(uint4*)&As[nb0 + t][co] = p;
    }
  }
  __syncthreads();

  // ---- 2) MFMA. Root frags loaded here (post-gather, TLP hides latency) ----
  int prow = node0 + l16;
  if (prow >= N) prow = N - 1;
  const ushort* hrow = hd + (size_t)prow * C128 + quad * 8;
  s16x8 aroot[4];
#pragma unroll
  for (int c = 0; c < 4; ++c) aroot[c] = *(const s16x8*)(hrow + c * 32);

  f32x4 acc[2];
  acc[0] = (f32x4)0.f;
  acc[1] = (f32x4)0.f;
  const ushort* wp = Wpack + lane * 8;
#pragma unroll
  for (int c = 0; c < 8; ++c) {
    s16x8 afr;
    if (c < 4) afr = *(const s16x8*)&As[l16][c * 32 + quad * 8];
    else       afr = aroot[c - 4];
#pragma unroll
    for (int j = 0; j < 2; ++j) {
      int nt = wave * 2 + j;
      s16x8 bfr = *(const s16x8*)(wp + (c * 8 + nt) * 512);
      acc[j] = __builtin_amdgcn_mfma_f32_16x16x32_bf16(afr, bfr, acc[j], 0, 0, 0);
    }
  }

  // ---- 3) epilogue. C/D layout: col = lane&15, row = quad*4 + reg ----
  float bv[2];
#pragma unroll
  for (int j = 0; j < 2; ++j) bv[j] = bias[(wave * 2 + j) * 16 + l16];

  if (mode) {
    ushort* ob = (ushort*)outp;
#pragma unroll
    for (int r = 0; r < 4; ++r) {
      int node = node0 + quad * 4 + r;
      if (node >= N) continue;
      unsigned kw = kb[node * 4 + wave];   // broadcast within 16-lane group
#pragma unroll
      for (int j = 0; j < 2; ++j) {
        int o = (wave * 2 + j) * 16 + l16;
        float v = fmaxf(acc[j][r] + bv[j], 0.f);
        ob[(size_t)node * C128 + o] =
            ((kw >> (j * 16 + l16)) & 1u) ? f2bf(v * 2.5f) : (ushort)0;
      }
    }
  } else {
    float* of = (float*)outp;
#pragma unroll
    for (int r = 0; r < 4; ++r) {
      int node = node0 + quad * 4 + r;
      if (node >= N) continue;
#pragma unroll
      for (int j = 0; j < 2; ++j) {
        int o = (wave * 2 + j) * 16 + l16;
        of[(size_t)node * C128 + o] = acc[j][r] + bv[j];
      }
    }
  }
}

// ---------------------------------------------------------------------------
extern "C" void kernel_launch(void* const* d_in, const int* in_sizes, int n_in,
                              void* d_out, int out_size, void* d_ws, size_t ws_size,
                              hipStream_t stream) {
  const float* x      = (const float*)d_in[0];
  const int*   eidx   = (const int*)d_in[1];
  const float* Wrel0  = (const float*)d_in[2];
  const float* Wroot0 = (const float*)d_in[3];
  const float* b0     = (const float*)d_in[4];
  const float* Wrel1  = (const float*)d_in[5];
  const float* Wroot1 = (const float*)d_in[6];
  const float* b1     = (const float*)d_in[7];
  const float* Wrel2  = (const float*)d_in[8];
  const float* Wroot2 = (const float*)d_in[9];
  const float* b2     = (const float*)d_in[10];
  const void*  drop0  = d_in[11];
  const void*  drop1  = d_in[12];
  const void*  drop2  = d_in[13];

  const int N       = in_sizes[0] / C128;
  const int E       = in_sizes[1] / 2;
  const int NC      = N * C128;
  const int nbuck16 = (N + 15) / 16;
  const int Npad    = nbuck16 * 16;
  const int NpadZ   = ((Npad + 63) / 64) * 64;   // 64-aligned range size
  const int nL4     = Npad * CAPN / 8;  // nlist size in uint4 units
  const int NW      = N * 4;            // mask words per layer
  const int qcap    = ((E / NSEG + 4096 + 255) / 256) * 256;

  char*     ws    = (char*)d_ws;
  ushort*   Wpack = (ushort*)ws;                          // 196608 B
  int*      ncnt  = (int*)(Wpack + 3 * 32768);            // Npad ints
  unsigned* kb1   = (unsigned*)(ncnt + Npad);             // Npad*4 uints
  unsigned* kb2   = kb1 + (size_t)Npad * 4;               // Npad*4 uints
  int*      qcnt  = (int*)(kb2 + (size_t)Npad * 4);       // 16 ints (8 used)
  unsigned* queue = (unsigned*)(qcnt + 16);               // NSEG*qcap uints
  ushort*   nlist = (ushort*)(queue + (size_t)NSEG * qcap);
  ushort*   hdA   = (ushort*)(nlist + (size_t)Npad * CAPN);
  ushort*   hdB   = hdA + NC;

  const ushort* Wp0 = Wpack;
  const ushort* Wp1 = Wpack + 32768;
  const ushort* Wp2 = Wpack + 2 * 32768;

  hipMemsetAsync(qcnt, 0, 16 * sizeof(int), stream);

  const int n4    = NC / 4;
  const int prepT = n4 + 3 * 32768 + NpadZ + nL4 + 2 * NW + E;
  prep_kernel<<<(prepT + 255) / 256, 256, 0, stream>>>(
      Wrel0, Wroot0, Wrel1, Wroot1, Wrel2, Wroot2, Wpack,
      x, drop0, drop1, drop2, eidx, hdA, kb1, kb2, n4, ncnt, Npad, NpadZ,
      (uint4*)nlist, nL4, NW, qcnt, queue, qcap, E);

  const int fillbB = NSEG * ((qcap + 255) / 256);
  fillb_kernel<<<fillbB, 256, 0, stream>>>(qcnt, queue, ncnt, nlist, qcap);

  // layer 0: hdA -> hdB (relu + drop1 fused)
  layer_kernel<<<nbuck16, 256, 0, stream>>>(hdA, ncnt, nlist, Wp0, b0, kb1,
                                            hdB, 1, N);
  // layer 1: hdB -> hdA (relu + drop2 fused)
  layer_kernel<<<nbuck16, 256, 0, stream>>>(hdB, ncnt, nlist, Wp1, b1, kb2,
                                            hdA, 1, N);
  // layer 2: hdA -> d_out (fp32)
  layer_kernel<<<nbuck16, 256, 0, stream>>>(hdA, ncnt, nlist, Wp2, b2, nullptr,
                                            d_out, 0, N);
}

// Round 9
// 335.184 us; speedup vs baseline: 4.2763x; 4.2763x over previous
//
#include <hip/hip_runtime.h>

// GraphConv x3 on MI355X. R17: R16 with queue-counter contention fixed.
// R16's 8 qcnt words shared ONE cache line -> 100K cross-XCD atomic line
// migrations -> prep 1160us at 0.85% VALU. Now counters are (seg, bucket=
// blockIdx&31), each on its own 64B line; bucket&7 == XCD under round-robin
// so every atomic is XCD-LOCAL (no migration), 256 independent counters.
// Queue = 256 sub-queues (qcapSB slots, 23-sigma slack). fillb grid keeps
// seg = blockIdx&7 -> nlist/ncnt scatter stays XCD-local (R14 property).
// Layers frozen = R14 (async global_load_lds gather @ ~2.45 TB/s floor).

#define C128 128
#define CAPN 64     // records per node; mean deg 16, Poisson tail ~1e-18
#define NSEG 8
#define NBKT 32     // counter buckets per segment (blockIdx&31)

typedef short s16x8 __attribute__((ext_vector_type(8)));
typedef float f32x4 __attribute__((ext_vector_type(4)));

__device__ __forceinline__ ushort f2bf(float f) {        // RNE fp32->bf16
  unsigned u = __builtin_bit_cast(unsigned, f);
  u = (u + 0x7FFFu + ((u >> 16) & 1u)) >> 16;
  return (ushort)u;
}
__device__ __forceinline__ float bflo(unsigned v) {
  return __builtin_bit_cast(float, v << 16);
}
__device__ __forceinline__ float bfhi(unsigned v) {
  return __builtin_bit_cast(float, v & 0xFFFF0000u);
}
__device__ __forceinline__ unsigned pack2(float lo, float hi) {
  return (unsigned)f2bf(lo) | ((unsigned)f2bf(hi) << 16);
}
// async 16B global->LDS; lane i deposits at l + i*16; g is per-lane.
__device__ __forceinline__ void gload_lds16(const void* g, void* l) {
  __builtin_amdgcn_global_load_lds(
      (const __attribute__((address_space(1))) void*)g,
      (__attribute__((address_space(3))) void*)l, 16, 0, 0);
}
// mask dtype probe: 1 if mask is int32 (all of first 16 words are 0/1),
// 0 if uint8 (byte-packed 0/1 -> words like 0x00010001 > 1).
__device__ __forceinline__ int probe_m32(const void* msk) {
  const uint4* p = (const uint4*)msk;
  int m32 = 1;
#pragma unroll
  for (int i = 0; i < 4; ++i) {
    uint4 q = p[i];
    if (q.x > 1u || q.y > 1u || q.z > 1u || q.w > 1u) m32 = 0;
  }
  return m32;
}

// ---------------------------------------------------------------------------
// prep: fused {input dropout fp32->bf16} + {weight pack} + {ncnt zero} +
// {nlist zero} + {bit-pack drop1/drop2} + {edge-pack queue append}.
// Thread partition (EVERY range 64-aligned so waves never straddle):
// [n4 dropout][98304 pack][NpadZ ncnt][nL4z nlist][2*NW kb][E edge-append].
// Wpack idx = (c*8+nt)*512 + lane*8 + j ->
//   W[o=nt*16+(lane&15)][k=(c&3)*32+(lane>>4)*8+j]; c<4 Wrel, c>=4 Wroot.
// kb layout: kb[node*4 + w] bit b = keep(channel w*32+b).
// queue: seg=(dst>>4)&7, bucket=blockIdx&31; rec = src<<16|dst;
// leader-based wave-agg append onto line-padded XCD-local counters.
// ---------------------------------------------------------------------------
__global__ __launch_bounds__(256) void prep_kernel(const float* __restrict__ Wr0,
                                                   const float* __restrict__ Wt0,
                                                   const float* __restrict__ Wr1,
                                                   const float* __restrict__ Wt1,
                                                   const float* __restrict__ Wr2,
                                                   const float* __restrict__ Wt2,
                                                   ushort* __restrict__ Wpack,
                                                   const float* __restrict__ x,
                                                   const void* __restrict__ mask0,
                                                   const void* __restrict__ mask1,
                                                   const void* __restrict__ mask2,
                                                   const int* __restrict__ eidx,
                                                   ushort* __restrict__ hdA,
                                                   unsigned* __restrict__ kb1,
                                                   unsigned* __restrict__ kb2,
                                                   int n4,
                                                   int* __restrict__ ncnt,
                                                   int Npad, int NpadZ,
                                                   uint4* __restrict__ nlist4,
                                                   int nL4, int nL4z, int NW,
                                                   int* __restrict__ qcnt2,
                                                   unsigned* __restrict__ queue,
                                                   int qcapSB, int E) {
  int t = blockIdx.x * 256 + threadIdx.x;
  if (t < n4) {
    int m32 = probe_m32(mask0);
    float4 v = ((const float4*)x)[t];
    int k0, k1, k2, k3;
    if (m32) {
      int4 m = ((const int4*)mask0)[t];
      k0 = m.x; k1 = m.y; k2 = m.z; k3 = m.w;
    } else {
      uchar4 m = ((const uchar4*)mask0)[t];
      k0 = m.x; k1 = m.y; k2 = m.z; k3 = m.w;
    }
    ushort4 r;
    r.x = k0 ? f2bf(v.x * 2.5f) : (ushort)0;
    r.y = k1 ? f2bf(v.y * 2.5f) : (ushort)0;
    r.z = k2 ? f2bf(v.z * 2.5f) : (ushort)0;
    r.w = k3 ? f2bf(v.w * 2.5f) : (ushort)0;
    ((ushort4*)hdA)[t] = r;
    return;
  }
  int u = t - n4;
  if (u < 3 * 32768) {
    int L = u >> 15;
    int r = u & 32767;
    int c = r >> 12;
    int nt = (r >> 9) & 7;
    int lane = (r >> 3) & 63;
    int j = r & 7;
    int o = nt * 16 + (lane & 15);
    int k = (c & 3) * 32 + (lane >> 4) * 8 + j;
    const float* src;
    if (L == 0)      src = (c < 4) ? Wr0 : Wt0;
    else if (L == 1) src = (c < 4) ? Wr1 : Wt1;
    else             src = (c < 4) ? Wr2 : Wt2;
    Wpack[u] = f2bf(src[o * C128 + k]);
    return;
  }
  u -= 3 * 32768;
  if (u < NpadZ) {
    if (u < Npad) ncnt[u] = 0;
    return;
  }
  u -= NpadZ;
  if (u < nL4z) {
    if (u < nL4) {
      uint4 zero; zero.x = 0; zero.y = 0; zero.z = 0; zero.w = 0;
      nlist4[u] = zero;
    }
    return;
  }
  u -= nL4z;
  if (u < 2 * NW) {
    const int L = (u >= NW);
    const int w = L ? u - NW : u;          // word id: node = w>>2, k = w&3
    const void* msk = L ? mask2 : mask1;
    const int n = w >> 2, k = w & 3;
    const int m32 = probe_m32(msk);
    unsigned wb = 0;
    if (m32) {
      const int4* b = (const int4*)msk + n * 32 + k * 8;
#pragma unroll
      for (int i = 0; i < 8; ++i) {
        int4 mm = b[i];
        wb |= (mm.x ? 1u : 0u) << (4 * i);
        wb |= (mm.y ? 1u : 0u) << (4 * i + 1);
        wb |= (mm.z ? 1u : 0u) << (4 * i + 2);
        wb |= (mm.w ? 1u : 0u) << (4 * i + 3);
      }
    } else {
      const uchar4* b = (const uchar4*)msk + n * 32 + k * 8;
#pragma unroll
      for (int i = 0; i < 8; ++i) {
        uchar4 mm = b[i];
        wb |= (mm.x ? 1u : 0u) << (4 * i);
        wb |= (mm.y ? 1u : 0u) << (4 * i + 1);
        wb |= (mm.z ? 1u : 0u) << (4 * i + 2);
        wb |= (mm.w ? 1u : 0u) << (4 * i + 3);
      }
    }
    (L ? kb2 : kb1)[n * 4 + k] = wb;
    return;
  }
  u -= 2 * NW;
  if (u < E) {
    // ---- edge-pack append (range 64-aligned; full waves) ----
    const int lane = threadIdx.x & 63;
    unsigned long long be = __ballot(eidx[2 * lane + 1] != 0);
    const int e64 = (be == 0ull);   // 1 = edges are int64
    int src, dst;
    if (e64) { src = eidx[2 * u]; dst = eidx[2 * E + 2 * u]; }
    else     { src = eidx[u];     dst = eidx[E + u]; }
    const int seg = (dst >> 4) & (NSEG - 1);
    const int bucket = blockIdx.x & (NBKT - 1);   // bucket&7 == this XCD
    const unsigned rec = ((unsigned)src << 16) | (unsigned)dst;
    int pos = 0;
#pragma unroll
    for (int s = 0; s < NSEG; ++s) {
      unsigned long long bm = __ballot(seg == s);
      if (bm == 0ull) continue;                       // wave-uniform
      const int leader = (int)(__ffsll((long long)bm) - 1);
      int b = 0;
      if (lane == leader)
        b = atomicAdd(&qcnt2[(s * NBKT + bucket) * 16], __popcll(bm));
      b = __shfl(b, leader, 64);
      if (seg == s)
        pos = b + __popcll(bm & ((1ull << lane) - 1ull));
    }
    if (pos < qcapSB)
      queue[(size_t)(seg * NBKT + bucket) * qcapSB + pos] = rec;
  }
}

// ---------------------------------------------------------------------------
// fillb: scatter-only. blockIdx = ((bucket*chunks + chunk) * 8) + seg so
// seg = blockIdx&7 (XCD proxy matches the layer grid: seg=(dst>>4)&7).
// Reads its compact sub-queue (coalesced 4B) and scatters XCD-locally.
// ---------------------------------------------------------------------------
__global__ __launch_bounds__(256) void fillb_kernel(const int* __restrict__ qcnt2,
                                                    const unsigned* __restrict__ queue,
                                                    int* __restrict__ ncnt,
                                                    ushort* __restrict__ nlist,
                                                    int qcapSB, int chunks) {
  const int seg = blockIdx.x & (NSEG - 1);
  const int rest = blockIdx.x >> 3;
  const int bucket = rest / chunks;
  const int chunk = rest - bucket * chunks;
  int qn = qcnt2[(seg * NBKT + bucket) * 16];
  if (qn > qcapSB) qn = qcapSB;
  const int i = chunk * 256 + threadIdx.x;
  if (i >= qn) return;
  const unsigned rec = queue[(size_t)(seg * NBKT + bucket) * qcapSB + i];
  const int dst = (int)(rec & 0xFFFFu);
  const int src = (int)(rec >> 16);
  int pos = atomicAdd(&ncnt[dst], 1);
  if (pos < CAPN) nlist[(size_t)dst * CAPN + pos] = (ushort)src;
}

// ---------------------------------------------------------------------------
// Fused layer: block = 16 nodes, 4 waves, wave w owns nodes 4w..4w+3.
//  0) stage: coalesced 512B list load per wave -> wl LDS + 16 coalesced
//     degree loads.
//  1) gather: async global_load_lds chunks (4 nodes x 4 edges = 4KB),
//     double-buffered; counted s_waitcnt vmcnt(4) mid-loop; predicated fma;
//     pad edges read row 0 (nlist zero-filled). xor-shfl reduce over quads;
//     quad-0 deposits bf16 rows into As. 1 barrier.
//  2) MFMA: wave w -> col tiles {2w,2w+1}; agg half from LDS, root half
//     loaded post-gather; B frags from Wpack (L2-hot).
//  3) epilogue: mode=1 ReLU + bit-packed next-dropout -> bf16 (mask word =
//     kb[node*4+wave], bit j*16+l16); mode=0 +bias -> fp32.
// ---------------------------------------------------------------------------
__global__ __launch_bounds__(256, 4) void layer_kernel(const ushort* __restrict__ hd,
                                                       const int* __restrict__ ncnt,
                                                       const ushort* __restrict__ nlist,
                                                       const ushort* __restrict__ Wpack,
                                                       const float* __restrict__ bias,
                                                       const unsigned* __restrict__ kb,
                                                       void* __restrict__ outp,
                                                       int mode, int N) {
  __shared__ ushort wl[16][CAPN];       // per-wave 4-row slices (512B/wave)
  __shared__ ushort As[16][136];        // 16 node rows, pad 8 (16B rows)
  __shared__ ushort gbuf[4][2][2048];   // per-wave dbuf: 2 x 4KB chunks

  const int tid = threadIdx.x;
  const int wave = tid >> 6, lane = tid & 63;
  const int quad = lane >> 4, l16 = lane & 15, co = l16 * 8;
  const int node0 = blockIdx.x * 16;
  const int nb0 = wave * 4;

  // ---- 0) stage: degrees + this wave's 4 node lists ----
  int deg16 = ncnt[node0 + l16];
  if (deg16 > CAPN) deg16 = CAPN;
  ((uint2*)&wl[nb0][0])[lane] =
      ((const uint2*)(nlist + (size_t)(node0 + nb0) * CAPN))[lane];

  int dc[4];
#pragma unroll
  for (int t = 0; t < 4; ++t) dc[t] = __shfl(deg16, nb0 + t, 64);
  int m = dc[0];
  if (dc[1] > m) m = dc[1];
  if (dc[2] > m) m = dc[2];
  if (dc[3] > m) m = dc[3];

  // ---- 1) gather: async LDS chunks, 4 edges/node/chunk ----
  const ushort* base = hd + co;
  float ag[4][8];
#pragma unroll
  for (int t = 0; t < 4; ++t)
#pragma unroll
    for (int i = 0; i < 8; ++i) ag[t][i] = 0.f;

  const int C = (m + 3) >> 2;          // wave-uniform chunk count (<=16)

#define ISSUE(c_, b_)                                                     \
  {                                                                       \
    const int e_ = ((c_) << 2) + quad;                                    \
    _Pragma("unroll")                                                     \
    for (int t_ = 0; t_ < 4; ++t_) {                                      \
      const ushort* g_ = base + (size_t)wl[nb0 + t_][e_] * C128;          \
      gload_lds16(g_, &gbuf[wave][b_][t_ * 512]);                         \
    }                                                                     \
  }

  if (C > 0) ISSUE(0, 0)
  if (C > 1) ISSUE(1, 1)

  for (int c = 0; c < C; ++c) {
    if (c + 1 < C) {
      asm volatile("s_waitcnt vmcnt(4)" ::: "memory");   // chunk c landed
    } else {
      asm volatile("s_waitcnt vmcnt(0)" ::: "memory");
    }
    __builtin_amdgcn_sched_barrier(0);
    const ushort* rb = &gbuf[wave][c & 1][lane * 8];
    const int e0 = (c << 2) + quad;
#pragma unroll
    for (int t = 0; t < 4; ++t) {
      uint4 v = *(const uint4*)(rb + t * 512);
      const float k = (e0 < dc[t]) ? 1.f : 0.f;
      ag[t][0] = fmaf(k, bflo(v.x), ag[t][0]);
      ag[t][1] = fmaf(k, bfhi(v.x), ag[t][1]);
      ag[t][2] = fmaf(k, bflo(v.y), ag[t][2]);
      ag[t][3] = fmaf(k, bfhi(v.y), ag[t][3]);
      ag[t][4] = fmaf(k, bflo(v.z), ag[t][4]);
      ag[t][5] = fmaf(k, bfhi(v.z), ag[t][5]);
      ag[t][6] = fmaf(k, bflo(v.w), ag[t][6]);
      ag[t][7] = fmaf(k, bfhi(v.w), ag[t][7]);
    }
    if (c + 2 < C) ISSUE(c + 2, c & 1)
  }
#undef ISSUE

#pragma unroll
  for (int t = 0; t < 4; ++t) {
#pragma unroll
    for (int i = 0; i < 8; ++i) {
      float v = ag[t][i];
      v += __shfl_xor(v, 16, 64);
      v += __shfl_xor(v, 32, 64);
      ag[t][i] = v;
    }
    if (quad == 0) {
      uint4 p;
      p.x = pack2(ag[t][0], ag[t][1]);
      p.y = pack2(ag[t][2], ag[t][3]);
      p.z = pack2(ag[t][4], ag[t][5]);
      p.w = pack2(ag[t][6], ag[t][7]);
      *(uint4*)&As[nb0 + t][co] = p;
    }
  }
  __syncthreads();

  // ---- 2) MFMA. Root frags loaded here (post-gather, TLP hides latency) ----
  int prow = node0 + l16;
  if (prow >= N) prow = N - 1;
  const ushort* hrow = hd + (size_t)prow * C128 + quad * 8;
  s16x8 aroot[4];
#pragma unroll
  for (int c = 0; c < 4; ++c) aroot[c] = *(const s16x8*)(hrow + c * 32);

  f32x4 acc[2];
  acc[0] = (f32x4)0.f;
  acc[1] = (f32x4)0.f;
  const ushort* wp = Wpack + lane * 8;
#pragma unroll
  for (int c = 0; c < 8; ++c) {
    s16x8 afr;
    if (c < 4) afr = *(const s16x8*)&As[l16][c * 32 + quad * 8];
    else       afr = aroot[c - 4];
#pragma unroll
    for (int j = 0; j < 2; ++j) {
      int nt = wave * 2 + j;
      s16x8 bfr = *(const s16x8*)(wp + (c * 8 + nt) * 512);
      acc[j] = __builtin_amdgcn_mfma_f32_16x16x32_bf16(afr, bfr, acc[j], 0, 0, 0);
    }
  }

  // ---- 3) epilogue. C/D layout: col = lane&15, row = quad*4 + reg ----
  float bv[2];
#pragma unroll
  for (int j = 0; j < 2; ++j) bv[j] = bias[(wave * 2 + j) * 16 + l16];

  if (mode) {
    ushort* ob = (ushort*)outp;
#pragma unroll
    for (int r = 0; r < 4; ++r) {
      int node = node0 + quad * 4 + r;
      if (node >= N) continue;
      unsigned kw = kb[node * 4 + wave];   // broadcast within 16-lane group
#pragma unroll
      for (int j = 0; j < 2; ++j) {
        int o = (wave * 2 + j) * 16 + l16;
        float v = fmaxf(acc[j][r] + bv[j], 0.f);
        ob[(size_t)node * C128 + o] =
            ((kw >> (j * 16 + l16)) & 1u) ? f2bf(v * 2.5f) : (ushort)0;
      }
    }
  } else {
    float* of = (float*)outp;
#pragma unroll
    for (int r = 0; r < 4; ++r) {
      int node = node0 + quad * 4 + r;
      if (node >= N) continue;
#pragma unroll
      for (int j = 0; j < 2; ++j) {
        int o = (wave * 2 + j) * 16 + l16;
        of[(size_t)node * C128 + o] = acc[j][r] + bv[j];
      }
    }
  }
}

// ---------------------------------------------------------------------------
extern "C" void kernel_launch(void* const* d_in, const int* in_sizes, int n_in,
                              void* d_out, int out_size, void* d_ws, size_t ws_size,
                              hipStream_t stream) {
  const float* x      = (const float*)d_in[0];
  const int*   eidx   = (const int*)d_in[1];
  const float* Wrel0  = (const float*)d_in[2];
  const float* Wroot0 = (const float*)d_in[3];
  const float* b0     = (const float*)d_in[4];
  const float* Wrel1  = (const float*)d_in[5];
  const float* Wroot1 = (const float*)d_in[6];
  const float* b1     = (const float*)d_in[7];
  const float* Wrel2  = (const float*)d_in[8];
  const float* Wroot2 = (const float*)d_in[9];
  const float* b2     = (const float*)d_in[10];
  const void*  drop0  = d_in[11];
  const void*  drop1  = d_in[12];
  const void*  drop2  = d_in[13];

  const int N       = in_sizes[0] / C128;
  const int E       = in_sizes[1] / 2;
  const int NC      = N * C128;
  const int nbuck16 = (N + 15) / 16;
  const int Npad    = nbuck16 * 16;
  const int NpadZ   = ((Npad + 63) / 64) * 64;     // 64-aligned range size
  const int nL4     = Npad * CAPN / 8;             // nlist size in uint4
  const int nL4z    = ((nL4 + 63) / 64) * 64;      // 64-aligned range size
  const int NW      = N * 4;                        // mask words per layer
  // per-(seg,bucket) sub-queue capacity: mean E/(8*32) + ~23 sigma slack
  const int qcapSB  = ((E / (NSEG * NBKT) + 1024 + 255) / 256) * 256;
  const int chunks  = qcapSB / 256;

  char*     ws    = (char*)d_ws;
  ushort*   Wpack = (ushort*)ws;                          // 196608 B
  int*      ncnt  = (int*)(Wpack + 3 * 32768);            // Npad ints
  unsigned* kb1   = (unsigned*)(ncnt + Npad);             // Npad*4 uints
  unsigned* kb2   = kb1 + (size_t)Npad * 4;               // Npad*4 uints
  int*      qcnt2 = (int*)(kb2 + (size_t)Npad * 4);       // 256*16 ints
  unsigned* queue = (unsigned*)(qcnt2 + NSEG * NBKT * 16);// 256*qcapSB uints
  ushort*   nlist = (ushort*)(queue + (size_t)NSEG * NBKT * qcapSB);
  ushort*   hdA   = (ushort*)(nlist + (size_t)Npad * CAPN);
  ushort*   hdB   = hdA + NC;

  const ushort* Wp0 = Wpack;
  const ushort* Wp1 = Wpack + 32768;
  const ushort* Wp2 = Wpack + 2 * 32768;

  hipMemsetAsync(qcnt2, 0, NSEG * NBKT * 16 * sizeof(int), stream);

  const int n4    = NC / 4;
  const int prepT = n4 + 3 * 32768 + NpadZ + nL4z + 2 * NW + E;
  prep_kernel<<<(prepT + 255) / 256, 256, 0, stream>>>(
      Wrel0, Wroot0, Wrel1, Wroot1, Wrel2, Wroot2, Wpack,
      x, drop0, drop1, drop2, eidx, hdA, kb1, kb2, n4, ncnt, Npad, NpadZ,
      (uint4*)nlist, nL4, nL4z, NW, qcnt2, queue, qcapSB, E);

  const int fillbB = NSEG * NBKT * chunks;
  fillb_kernel<<<fillbB, 256, 0, stream>>>(qcnt2, queue, ncnt, nlist,
                                           qcapSB, chunks);

  // layer 0: hdA -> hdB (relu + drop1 fused)
  layer_kernel<<<nbuck16, 256, 0, stream>>>(hdA, ncnt, nlist, Wp0, b0, kb1,
                                            hdB, 1, N);
  // layer 1: hdB -> hdA (relu + drop2 fused)
  layer_kernel<<<nbuck16, 256, 0, stream>>>(hdB, ncnt, nlist, Wp1, b1, kb2,
                                            hdA, 1, N);
  // layer 2: hdA -> d_out (fp32)
  layer_kernel<<<nbuck16, 256, 0, stream>>>(hdA, ncnt, nlist, Wp2, b2, nullptr,
                                            d_out, 0, N);
}

// Round 10
// 329.904 us; speedup vs baseline: 4.3448x; 1.0160x over previous
//
#include <hip/hip_runtime.h>

// GraphConv x3 on MI355X. R18: prep latency fixes. R17's prep (51us) was
// latency-bound (VALU 16%, HBM 20%): (a) probe_m32 put a 4x16B dependent
// probe-load chain in front of EVERY dropout/kb thread's real mask load;
// (b) edge-append did 8 serialized ballot->atomic->shfl rounds. Now dtype
// detect = one 4B ballot load per wave; edge-append = 3-ballot match-any
// (one atomicAdd instruction, <=8 leader lanes, XCD-local lines) + 1 shfl.
// fillb + layers byte-identical to R17 (layers at gather fetch floor).

#define C128 128
#define CAPN 64     // records per node; mean deg 16, Poisson tail ~1e-18
#define NSEG 8
#define NBKT 32     // counter buckets per segment (blockIdx&31)

typedef short s16x8 __attribute__((ext_vector_type(8)));
typedef float f32x4 __attribute__((ext_vector_type(4)));

__device__ __forceinline__ ushort f2bf(float f) {        // RNE fp32->bf16
  unsigned u = __builtin_bit_cast(unsigned, f);
  u = (u + 0x7FFFu + ((u >> 16) & 1u)) >> 16;
  return (ushort)u;
}
__device__ __forceinline__ float bflo(unsigned v) {
  return __builtin_bit_cast(float, v << 16);
}
__device__ __forceinline__ float bfhi(unsigned v) {
  return __builtin_bit_cast(float, v & 0xFFFF0000u);
}
__device__ __forceinline__ unsigned pack2(float lo, float hi) {
  return (unsigned)f2bf(lo) | ((unsigned)f2bf(hi) << 16);
}
// async 16B global->LDS; lane i deposits at l + i*16; g is per-lane.
__device__ __forceinline__ void gload_lds16(const void* g, void* l) {
  __builtin_amdgcn_global_load_lds(
      (const __attribute__((address_space(1))) void*)g,
      (__attribute__((address_space(3))) void*)l, 16, 0, 0);
}
// wave-cheap mask dtype detect: word `lane` of the mask. int32 masks -> all
// words 0/1 -> ballot(>1)==0. uint8 masks -> some word has a byte>0 above
// bit 1 (P(miss) ~ 0.216^64 ~ 1e-43). ONE 4B L2-hot load per wave.
__device__ __forceinline__ int ballot_m32(const void* msk, int lane) {
  unsigned mv = ((const unsigned*)msk)[lane];
  return (__ballot(mv > 1u) == 0ull);
}

// ---------------------------------------------------------------------------
// prep: fused {input dropout fp32->bf16} + {weight pack} + {ncnt zero} +
// {nlist zero} + {bit-pack drop1/drop2} + {edge-pack queue append}.
// Thread partition (EVERY range 64-aligned so waves never straddle):
// [n4 dropout][98304 pack][NpadZ ncnt][nL4z nlist][2*NW kb][E edge-append].
// Wpack idx = (c*8+nt)*512 + lane*8 + j ->
//   W[o=nt*16+(lane&15)][k=(c&3)*32+(lane>>4)*8+j]; c<4 Wrel, c>=4 Wroot.
// kb layout: kb[node*4 + w] bit b = keep(channel w*32+b).
// queue: seg=(dst>>4)&7, bucket=blockIdx&31; rec = src<<16|dst;
// 3-ballot match-any wave-agg append onto line-padded XCD-local counters.
// ---------------------------------------------------------------------------
__global__ __launch_bounds__(256) void prep_kernel(const float* __restrict__ Wr0,
                                                   const float* __restrict__ Wt0,
                                                   const float* __restrict__ Wr1,
                                                   const float* __restrict__ Wt1,
                                                   const float* __restrict__ Wr2,
                                                   const float* __restrict__ Wt2,
                                                   ushort* __restrict__ Wpack,
                                                   const float* __restrict__ x,
                                                   const void* __restrict__ mask0,
                                                   const void* __restrict__ mask1,
                                                   const void* __restrict__ mask2,
                                                   const int* __restrict__ eidx,
                                                   ushort* __restrict__ hdA,
                                                   unsigned* __restrict__ kb1,
                                                   unsigned* __restrict__ kb2,
                                                   int n4,
                                                   int* __restrict__ ncnt,
                                                   int Npad, int NpadZ,
                                                   uint4* __restrict__ nlist4,
                                                   int nL4, int nL4z, int NW,
                                                   int* __restrict__ qcnt2,
                                                   unsigned* __restrict__ queue,
                                                   int qcapSB, int E) {
  int t = blockIdx.x * 256 + threadIdx.x;
  const int lane = threadIdx.x & 63;
  if (t < n4) {
    const int m32 = ballot_m32(mask0, lane);   // wave-uniform, 1 load
    float4 v = ((const float4*)x)[t];
    int k0, k1, k2, k3;
    if (m32) {
      int4 m = ((const int4*)mask0)[t];
      k0 = m.x; k1 = m.y; k2 = m.z; k3 = m.w;
    } else {
      uchar4 m = ((const uchar4*)mask0)[t];
      k0 = m.x; k1 = m.y; k2 = m.z; k3 = m.w;
    }
    ushort4 r;
    r.x = k0 ? f2bf(v.x * 2.5f) : (ushort)0;
    r.y = k1 ? f2bf(v.y * 2.5f) : (ushort)0;
    r.z = k2 ? f2bf(v.z * 2.5f) : (ushort)0;
    r.w = k3 ? f2bf(v.w * 2.5f) : (ushort)0;
    ((ushort4*)hdA)[t] = r;
    return;
  }
  int u = t - n4;
  if (u < 3 * 32768) {
    int L = u >> 15;
    int r = u & 32767;
    int c = r >> 12;
    int nt = (r >> 9) & 7;
    int ln = (r >> 3) & 63;
    int j = r & 7;
    int o = nt * 16 + (ln & 15);
    int k = (c & 3) * 32 + (ln >> 4) * 8 + j;
    const float* src;
    if (L == 0)      src = (c < 4) ? Wr0 : Wt0;
    else if (L == 1) src = (c < 4) ? Wr1 : Wt1;
    else             src = (c < 4) ? Wr2 : Wt2;
    Wpack[u] = f2bf(src[o * C128 + k]);
    return;
  }
  u -= 3 * 32768;
  if (u < NpadZ) {
    if (u < Npad) ncnt[u] = 0;
    return;
  }
  u -= NpadZ;
  if (u < nL4z) {
    if (u < nL4) {
      uint4 zero; zero.x = 0; zero.y = 0; zero.z = 0; zero.w = 0;
      nlist4[u] = zero;
    }
    return;
  }
  u -= nL4z;
  if (u < 2 * NW) {
    const int L = (u >= NW);                  // wave-uniform (NW % 64 == 0)
    const int w = L ? u - NW : u;             // word id: node = w>>2, k = w&3
    const void* msk = L ? mask2 : mask1;
    const int n = w >> 2, k = w & 3;
    const int m32 = ballot_m32(msk, lane);    // wave-uniform, 1 load
    unsigned wb = 0;
    if (m32) {
      const int4* b = (const int4*)msk + n * 32 + k * 8;
#pragma unroll
      for (int i = 0; i < 8; ++i) {
        int4 mm = b[i];
        wb |= (mm.x ? 1u : 0u) << (4 * i);
        wb |= (mm.y ? 1u : 0u) << (4 * i + 1);
        wb |= (mm.z ? 1u : 0u) << (4 * i + 2);
        wb |= (mm.w ? 1u : 0u) << (4 * i + 3);
      }
    } else {
      const uchar4* b = (const uchar4*)msk + n * 32 + k * 8;
#pragma unroll
      for (int i = 0; i < 8; ++i) {
        uchar4 mm = b[i];
        wb |= (mm.x ? 1u : 0u) << (4 * i);
        wb |= (mm.y ? 1u : 0u) << (4 * i + 1);
        wb |= (mm.z ? 1u : 0u) << (4 * i + 2);
        wb |= (mm.w ? 1u : 0u) << (4 * i + 3);
      }
    }
    (L ? kb2 : kb1)[n * 4 + k] = wb;
    return;
  }
  u -= 2 * NW;
  if (u < E) {
    // ---- edge-pack append (range 64-aligned; full waves) ----
    unsigned long long be = __ballot(eidx[2 * lane + 1] != 0);
    const int e64 = (be == 0ull);   // 1 = edges are int64
    int src, dst;
    if (e64) { src = eidx[2 * u]; dst = eidx[2 * E + 2 * u]; }
    else     { src = eidx[u];     dst = eidx[E + u]; }
    const int seg = (dst >> 4) & (NSEG - 1);
    const int bucket = blockIdx.x & (NBKT - 1);   // bucket&7 == this XCD
    const unsigned rec = ((unsigned)src << 16) | (unsigned)dst;
    // 3-ballot match-any: mask of lanes with my seg
    unsigned long long b0 = __ballot(seg & 1);
    unsigned long long b1 = __ballot(seg & 2);
    unsigned long long b2 = __ballot(seg & 4);
    unsigned long long me = ((seg & 1) ? b0 : ~b0) &
                            ((seg & 2) ? b1 : ~b1) &
                            ((seg & 4) ? b2 : ~b2);
    const int leader = (int)(__ffsll((long long)me) - 1);
    int base = 0;
    if (lane == leader)   // <=8 leader lanes, ONE atomic instruction,
      base = atomicAdd(&qcnt2[(seg * NBKT + bucket) * 16], __popcll(me));
    base = __shfl(base, leader, 64);
    const int pos = base + __popcll(me & ((1ull << lane) - 1ull));
    if (pos < qcapSB)
      queue[(size_t)(seg * NBKT + bucket) * qcapSB + pos] = rec;
  }
}

// ---------------------------------------------------------------------------
// fillb: scatter-only. blockIdx = ((bucket*chunks + chunk) * 8) + seg so
// seg = blockIdx&7 (XCD proxy matches the layer grid: seg=(dst>>4)&7).
// Reads its compact sub-queue (coalesced 4B) and scatters XCD-locally.
// ---------------------------------------------------------------------------
__global__ __launch_bounds__(256) void fillb_kernel(const int* __restrict__ qcnt2,
                                                    const unsigned* __restrict__ queue,
                                                    int* __restrict__ ncnt,
                                                    ushort* __restrict__ nlist,
                                                    int qcapSB, int chunks) {
  const int seg = blockIdx.x & (NSEG - 1);
  const int rest = blockIdx.x >> 3;
  const int bucket = rest / chunks;
  const int chunk = rest - bucket * chunks;
  int qn = qcnt2[(seg * NBKT + bucket) * 16];
  if (qn > qcapSB) qn = qcapSB;
  const int i = chunk * 256 + threadIdx.x;
  if (i >= qn) return;
  const unsigned rec = queue[(size_t)(seg * NBKT + bucket) * qcapSB + i];
  const int dst = (int)(rec & 0xFFFFu);
  const int src = (int)(rec >> 16);
  int pos = atomicAdd(&ncnt[dst], 1);
  if (pos < CAPN) nlist[(size_t)dst * CAPN + pos] = (ushort)src;
}

// ---------------------------------------------------------------------------
// Fused layer: block = 16 nodes, 4 waves, wave w owns nodes 4w..4w+3.
//  0) stage: coalesced 512B list load per wave -> wl LDS + 16 coalesced
//     degree loads.
//  1) gather: async global_load_lds chunks (4 nodes x 4 edges = 4KB),
//     double-buffered; counted s_waitcnt vmcnt(4) mid-loop; predicated fma;
//     pad edges read row 0 (nlist zero-filled). xor-shfl reduce over quads;
//     quad-0 deposits bf16 rows into As. 1 barrier.
//  2) MFMA: wave w -> col tiles {2w,2w+1}; agg half from LDS, root half
//     loaded post-gather; B frags from Wpack (L2-hot).
//  3) epilogue: mode=1 ReLU + bit-packed next-dropout -> bf16 (mask word =
//     kb[node*4+wave], bit j*16+l16); mode=0 +bias -> fp32.
// ---------------------------------------------------------------------------
__global__ __launch_bounds__(256, 4) void layer_kernel(const ushort* __restrict__ hd,
                                                       const int* __restrict__ ncnt,
                                                       const ushort* __restrict__ nlist,
                                                       const ushort* __restrict__ Wpack,
                                                       const float* __restrict__ bias,
                                                       const unsigned* __restrict__ kb,
                                                       void* __restrict__ outp,
                                                       int mode, int N) {
  __shared__ ushort wl[16][CAPN];       // per-wave 4-row slices (512B/wave)
  __shared__ ushort As[16][136];        // 16 node rows, pad 8 (16B rows)
  __shared__ ushort gbuf[4][2][2048];   // per-wave dbuf: 2 x 4KB chunks

  const int tid = threadIdx.x;
  const int wave = tid >> 6, lane = tid & 63;
  const int quad = lane >> 4, l16 = lane & 15, co = l16 * 8;
  const int node0 = blockIdx.x * 16;
  const int nb0 = wave * 4;

  // ---- 0) stage: degrees + this wave's 4 node lists ----
  int deg16 = ncnt[node0 + l16];
  if (deg16 > CAPN) deg16 = CAPN;
  ((uint2*)&wl[nb0][0])[lane] =
      ((const uint2*)(nlist + (size_t)(node0 + nb0) * CAPN))[lane];

  int dc[4];
#pragma unroll
  for (int t = 0; t < 4; ++t) dc[t] = __shfl(deg16, nb0 + t, 64);
  int m = dc[0];
  if (dc[1] > m) m = dc[1];
  if (dc[2] > m) m = dc[2];
  if (dc[3] > m) m = dc[3];

  // ---- 1) gather: async LDS chunks, 4 edges/node/chunk ----
  const ushort* base = hd + co;
  float ag[4][8];
#pragma unroll
  for (int t = 0; t < 4; ++t)
#pragma unroll
    for (int i = 0; i < 8; ++i) ag[t][i] = 0.f;

  const int C = (m + 3) >> 2;          // wave-uniform chunk count (<=16)

#define ISSUE(c_, b_)                                                     \
  {                                                                       \
    const int e_ = ((c_) << 2) + quad;                                    \
    _Pragma("unroll")                                                     \
    for (int t_ = 0; t_ < 4; ++t_) {                                      \
      const ushort* g_ = base + (size_t)wl[nb0 + t_][e_] * C128;          \
      gload_lds16(g_, &gbuf[wave][b_][t_ * 512]);                         \
    }                                                                     \
  }

  if (C > 0) ISSUE(0, 0)
  if (C > 1) ISSUE(1, 1)

  for (int c = 0; c < C; ++c) {
    if (c + 1 < C) {
      asm volatile("s_waitcnt vmcnt(4)" ::: "memory");   // chunk c landed
    } else {
      asm volatile("s_waitcnt vmcnt(0)" ::: "memory");
    }
    __builtin_amdgcn_sched_barrier(0);
    const ushort* rb = &gbuf[wave][c & 1][lane * 8];
    const int e0 = (c << 2) + quad;
#pragma unroll
    for (int t = 0; t < 4; ++t) {
      uint4 v = *(const uint4*)(rb + t * 512);
      const float k = (e0 < dc[t]) ? 1.f : 0.f;
      ag[t][0] = fmaf(k, bflo(v.x), ag[t][0]);
      ag[t][1] = fmaf(k, bfhi(v.x), ag[t][1]);
      ag[t][2] = fmaf(k, bflo(v.y), ag[t][2]);
      ag[t][3] = fmaf(k, bfhi(v.y), ag[t][3]);
      ag[t][4] = fmaf(k, bflo(v.z), ag[t][4]);
      ag[t][5] = fmaf(k, bfhi(v.z), ag[t][5]);
      ag[t][6] = fmaf(k, bflo(v.w), ag[t][6]);
      ag[t][7] = fmaf(k, bfhi(v.w), ag[t][7]);
    }
    if (c + 2 < C) ISSUE(c + 2, c & 1)
  }
#undef ISSUE

#pragma unroll
  for (int t = 0; t < 4; ++t) {
#pragma unroll
    for (int i = 0; i < 8; ++i) {
      float v = ag[t][i];
      v += __shfl_xor(v, 16, 64);
      v += __shfl_xor(v, 32, 64);
      ag[t][i] = v;
    }
    if (quad == 0) {
      uint4 p;
      p.x = pack2(ag[t][0], ag[t][1]);
      p.y = pack2(ag[t][2], ag[t][3]);
      p.z = pack2(ag[t][4], ag[t][5]);
      p.w = pack2(ag[t][6], ag[t][7]);
      *(uint4*)&As[nb0 + t][co] = p;
    }
  }
  __syncthreads();

  // ---- 2) MFMA. Root frags loaded here (post-gather, TLP hides latency) ----
  int prow = node0 + l16;
  if (prow >= N) prow = N - 1;
  const ushort* hrow = hd + (size_t)prow * C128 + quad * 8;
  s16x8 aroot[4];
#pragma unroll
  for (int c = 0; c < 4; ++c) aroot[c] = *(const s16x8*)(hrow + c * 32);

  f32x4 acc[2];
  acc[0] = (f32x4)0.f;
  acc[1] = (f32x4)0.f;
  const ushort* wp = Wpack + lane * 8;
#pragma unroll
  for (int c = 0; c < 8; ++c) {
    s16x8 afr;
    if (c < 4) afr = *(const s16x8*)&As[l16][c * 32 + quad * 8];
    else       afr = aroot[c - 4];
#pragma unroll
    for (int j = 0; j < 2; ++j) {
      int nt = wave * 2 + j;
      s16x8 bfr = *(const s16x8*)(wp + (c * 8 + nt) * 512);
      acc[j] = __builtin_amdgcn_mfma_f32_16x16x32_bf16(afr, bfr, acc[j], 0, 0, 0);
    }
  }

  // ---- 3) epilogue. C/D layout: col = lane&15, row = quad*4 + reg ----
  float bv[2];
#pragma unroll
  for (int j = 0; j < 2; ++j) bv[j] = bias[(wave * 2 + j) * 16 + l16];

  if (mode) {
    ushort* ob = (ushort*)outp;
#pragma unroll
    for (int r = 0; r < 4; ++r) {
      int node = node0 + quad * 4 + r;
      if (node >= N) continue;
      unsigned kw = kb[node * 4 + wave];   // broadcast within 16-lane group
#pragma unroll
      for (int j = 0; j < 2; ++j) {
        int o = (wave * 2 + j) * 16 + l16;
        float v = fmaxf(acc[j][r] + bv[j], 0.f);
        ob[(size_t)node * C128 + o] =
            ((kw >> (j * 16 + l16)) & 1u) ? f2bf(v * 2.5f) : (ushort)0;
      }
    }
  } else {
    float* of = (float*)outp;
#pragma unroll
    for (int r = 0; r < 4; ++r) {
      int node = node0 + quad * 4 + r;
      if (node >= N) continue;
#pragma unroll
      for (int j = 0; j < 2; ++j) {
        int o = (wave * 2 + j) * 16 + l16;
        of[(size_t)node * C128 + o] = acc[j][r] + bv[j];
      }
    }
  }
}

// ---------------------------------------------------------------------------
extern "C" void kernel_launch(void* const* d_in, const int* in_sizes, int n_in,
                              void* d_out, int out_size, void* d_ws, size_t ws_size,
                              hipStream_t stream) {
  const float* x      = (const float*)d_in[0];
  const int*   eidx   = (const int*)d_in[1];
  const float* Wrel0  = (const float*)d_in[2];
  const float* Wroot0 = (const float*)d_in[3];
  const float* b0     = (const float*)d_in[4];
  const float* Wrel1  = (const float*)d_in[5];
  const float* Wroot1 = (const float*)d_in[6];
  const float* b1     = (const float*)d_in[7];
  const float* Wrel2  = (const float*)d_in[8];
  const float* Wroot2 = (const float*)d_in[9];
  const float* b2     = (const float*)d_in[10];
  const void*  drop0  = d_in[11];
  const void*  drop1  = d_in[12];
  const void*  drop2  = d_in[13];

  const int N       = in_sizes[0] / C128;
  const int E       = in_sizes[1] / 2;
  const int NC      = N * C128;
  const int nbuck16 = (N + 15) / 16;
  const int Npad    = nbuck16 * 16;
  const int NpadZ   = ((Npad + 63) / 64) * 64;     // 64-aligned range size
  const int nL4     = Npad * CAPN / 8;             // nlist size in uint4
  const int nL4z    = ((nL4 + 63) / 64) * 64;      // 64-aligned range size
  const int NW      = N * 4;                        // mask words per layer
  // per-(seg,bucket) sub-queue capacity: mean E/(8*32) + ~23 sigma slack
  const int qcapSB  = ((E / (NSEG * NBKT) + 1024 + 255) / 256) * 256;
  const int chunks  = qcapSB / 256;

  char*     ws    = (char*)d_ws;
  ushort*   Wpack = (ushort*)ws;                          // 196608 B
  int*      ncnt  = (int*)(Wpack + 3 * 32768);            // Npad ints
  unsigned* kb1   = (unsigned*)(ncnt + Npad);             // Npad*4 uints
  unsigned* kb2   = kb1 + (size_t)Npad * 4;               // Npad*4 uints
  int*      qcnt2 = (int*)(kb2 + (size_t)Npad * 4);       // 256*16 ints
  unsigned* queue = (unsigned*)(qcnt2 + NSEG * NBKT * 16);// 256*qcapSB uints
  ushort*   nlist = (ushort*)(queue + (size_t)NSEG * NBKT * qcapSB);
  ushort*   hdA   = (ushort*)(nlist + (size_t)Npad * CAPN);
  ushort*   hdB   = hdA + NC;

  const ushort* Wp0 = Wpack;
  const ushort* Wp1 = Wpack + 32768;
  const ushort* Wp2 = Wpack + 2 * 32768;

  hipMemsetAsync(qcnt2, 0, NSEG * NBKT * 16 * sizeof(int), stream);

  const int n4    = NC / 4;
  const int prepT = n4 + 3 * 32768 + NpadZ + nL4z + 2 * NW + E;
  prep_kernel<<<(prepT + 255) / 256, 256, 0, stream>>>(
      Wrel0, Wroot0, Wrel1, Wroot1, Wrel2, Wroot2, Wpack,
      x, drop0, drop1, drop2, eidx, hdA, kb1, kb2, n4, ncnt, Npad, NpadZ,
      (uint4*)nlist, nL4, nL4z, NW, qcnt2, queue, qcapSB, E);

  const int fillbB = NSEG * NBKT * chunks;
  fillb_kernel<<<fillbB, 256, 0, stream>>>(qcnt2, queue, ncnt, nlist,
                                           qcapSB, chunks);

  // layer 0: hdA -> hdB (relu + drop1 fused)
  layer_kernel<<<nbuck16, 256, 0, stream>>>(hdA, ncnt, nlist, Wp0, b0, kb1,
                                            hdB, 1, N);
  // layer 1: hdB -> hdA (relu + drop2 fused)
  layer_kernel<<<nbuck16, 256, 0, stream>>>(hdB, ncnt, nlist, Wp1, b1, kb2,
                                            hdA, 1, N);
  // layer 2: hdA -> d_out (fp32)
  layer_kernel<<<nbuck16, 256, 0, stream>>>(hdA, ncnt, nlist, Wp2, b2, nullptr,
                                            d_out, 0, N);
}